// Round 12
// baseline (612.625 us; speedup 1.0000x reference)
//
#include <hip/hip_runtime.h>
#include <math.h>

#define NN 100000
#define NE 1600000
#define NT (NE + NN)   // 1700000 edges incl. self-loops
#define DD 128
#define NB 500          // dst buckets
#define BR 200          // node range per bucket (NB*BR == NN)
#define BCAP 4096       // bucket capacity (mean 3200, sigma 56 -> 15.9 sigma headroom)
#define NCH 2048        // edges per k_bucket block
#define NBK 782         // ceil(NE/NCH)
#define NBG 1563        // ceil(NN/64) gemm blocks
#define SLN 800000      // uints per H slice (NN * 8)
#define BMAGIC 21474837u // ceil(2^32/200); exact for d < 100000

typedef unsigned int uint;
typedef unsigned short ushort;
typedef __attribute__((ext_vector_type(8))) short bf16x8;
typedef __attribute__((ext_vector_type(4))) float f32x4;

// round-to-nearest-even fp32 -> bf16 (16-bit payload in a uint)
__device__ __forceinline__ uint bfr(float f){
  uint u = __float_as_uint(f);
  return (u + 0x7FFFu + ((u >> 16) & 1u)) >> 16;
}
__device__ __forceinline__ uint pk2(float a, float b){
  return (bfr(a) & 0xFFFFu) | (bfr(b) << 16);
}
__device__ __forceinline__ bf16x8 asbf(uint4 u){
  union { uint4 u; bf16x8 b; } c; c.u = u; return c.b;
}

// ---------------- init: weight transpose (blocks 0,1) + gcnt zero (block 2) ----------------
__global__ __launch_bounds__(256) void k_init(const float* __restrict__ W1f, const float* __restrict__ W2f,
    uint* __restrict__ Wt1, uint* __restrict__ Wt2, int* __restrict__ gcnt){
  int t = threadIdx.x;
  if (blockIdx.x == 2){
    for (int i = t; i < 8000; i += 256) gcnt[i] = 0;
    return;
  }
  const float* W = blockIdx.x ? W2f : W1f;
  uint* Wt = blockIdx.x ? Wt2 : Wt1;
  int n = t >> 1, k0 = (t & 1) * 64;
  for (int kk = 0; kk < 64; kk += 2){
    float v0 = W[(size_t)(k0+kk  )*DD + n];
    float v1 = W[(size_t)(k0+kk+1)*DD + n];
    Wt[(size_t)n*64 + ((k0+kk)>>1)] = pk2(v0, v1);
  }
}

// ---------------- preprocessing: 2-phase LDS-histogram bucket sort ----------------

__global__ __launch_bounds__(256) void k_bucket(const int* __restrict__ ei,
    int* __restrict__ gcnt, uint* __restrict__ bedge){
  __shared__ uint   ent[NCH];    // src(17b) | d_local(8b)<<17
  __shared__ ushort bbs[NCH];    // bucket id
  __shared__ int    hist[NB];
  __shared__ int    fl[NB];
  __shared__ int    gb[NB];
  int t = threadIdx.x;
  int base = blockIdx.x * NCH;
  int nv = NE - base; if (nv > NCH) nv = NCH;
  for (int b = t; b < NB; b += 256){ hist[b] = 0; fl[b] = 0; }
  __syncthreads();
  for (int j = t; j < nv; j += 256){
    int i = base + j;                      // coalesced
    uint s = (uint)ei[i];
    uint d = (uint)ei[NE + i];
    uint b = __umulhi(d, BMAGIC);          // d / 200
    uint dl = d - b*BR;
    ent[j] = s | (dl << 17);
    bbs[j] = (ushort)b;
    atomicAdd(&hist[b], 1);
  }
  __syncthreads();
  for (int b = t; b < NB; b += 256){
    int h = hist[b];
    gb[b] = h ? atomicAdd(&gcnt[b*16], h) : 0;   // bulk reservation
  }
  __syncthreads();
  for (int j = t; j < nv; j += 256){
    uint b = bbs[j];
    int q = atomicAdd(&fl[b], 1);          // LDS fill
    bedge[(size_t)b*BCAP + gb[b] + q] = ent[j];
  }
}

// single-block exclusive scan of bucket totals (incl. +BR self-loops each)
__global__ __launch_bounds__(512) void k_bscan(const int* __restrict__ gcnt, int* __restrict__ bbase){
  __shared__ int s[512];
  int t = threadIdx.x;
  int v = (t < NB) ? (gcnt[t*16] + BR) : 0;
  s[t] = v;
  __syncthreads();
  for (int off = 1; off < 512; off <<= 1){
    int a = (t >= off) ? s[t-off] : 0;
    __syncthreads();
    s[t] += a;
    __syncthreads();
  }
  if (t < NB) bbase[t] = s[t] - v;
}

// fused per-bucket CSR build: LDS count + scan -> dis/rowptr/es (es = plain src)
__global__ __launch_bounds__(256) void k_build(const int* __restrict__ gcnt,
    const int* __restrict__ bbase, const uint* __restrict__ bedge,
    float* __restrict__ dis, int* __restrict__ rowptr, uint* __restrict__ es){
  __shared__ uint eL[BCAP];
  __shared__ int  cl[BR];
  __shared__ int  fl[BR];
  __shared__ int  pf[256];
  int b = blockIdx.x, t = threadIdx.x;
  int base = bbase[b];
  if (t < BR){ cl[t] = 0; fl[t] = 0; }
  __syncthreads();
  int cnt = gcnt[b*16];
  for (int e = t; e < cnt; e += 256){
    uint u = bedge[(size_t)b*BCAP + e];
    eL[e] = u;
    atomicAdd(&cl[u >> 17], 1);
  }
  __syncthreads();
  // inclusive scan over (cl[i]+1)
  int v = (t < BR) ? (cl[t] + 1) : 0;
  pf[t] = v;
  __syncthreads();
  for (int off = 1; off < 256; off <<= 1){
    int a = (t >= off) ? pf[t-off] : 0;
    __syncthreads();
    pf[t] += a;
    __syncthreads();
  }
  if (t < BR){
    int n  = b*BR + t;
    int p0 = base + pf[t] - v;             // exclusive prefix (globally monotone)
    rowptr[n] = p0;
    dis[n] = rsqrtf((float)(cl[t] + 1));
    es[p0 + cl[t]] = (uint)n;              // self-loop last
  }
  if (b == NB-1 && t == 0) rowptr[NN] = NT;
  __syncthreads();
  for (int e = t; e < cnt; e += 256){
    uint u = eL[e];
    int  dloc = u >> 17;
    int  q  = atomicAdd(&fl[dloc], 1);
    int  p0 = base + pf[dloc] - (cl[dloc] + 1);
    es[p0 + q] = u & 0x1FFFFu;
  }
}

// ---------------- MFMA GEMM -> dis-scaled bf16, SLICE-MAJOR out ----------------
// Y[slice][r][8 uints]: slice = channel/16 -> each slice array is 3.2MB (fits
// a 4MB per-XCD L2) for the downstream gather. Zero-LDS; A = Wt rows, B = X rows;
// lane owns output row r = lane&15, cols nt*16 + g*4 + reg (HW-verified layout).
template<int IN_BF16>
__global__ __launch_bounds__(256) void k_gemm(const void* __restrict__ Xv,
    const uint* __restrict__ Wt, const float* __restrict__ dis,
    uint* __restrict__ Y, int nrows){
  int t = threadIdx.x;
  int wv = t >> 6, l = t & 63;
  int g = l >> 4, li = l & 15;
  int r = blockIdx.x*64 + wv*16 + li;     // this lane's X/output row
  bool valid = (r < nrows);

  f32x4 acc[8];
  #pragma unroll
  for (int i = 0; i < 8; ++i) acc[i] = (f32x4){0.f,0.f,0.f,0.f};

  #pragma unroll
  for (int ks = 0; ks < 4; ++ks){
    int k0 = ks*32 + g*8;                 // this lane's 8-element k-chunk
    uint4 xb;
    if (IN_BF16){
      xb = valid ? ((const uint4*)Xv)[(size_t)r*16 + (k0>>3)] : make_uint4(0,0,0,0);
    } else {
      if (valid){
        const float* X = (const float*)Xv;
        float4 f0 = ((const float4*)X)[(size_t)r*32 + (k0>>2)];
        float4 f1 = ((const float4*)X)[(size_t)r*32 + (k0>>2) + 1];
        xb.x = pk2(f0.x, f0.y); xb.y = pk2(f0.z, f0.w);
        xb.z = pk2(f1.x, f1.y); xb.w = pk2(f1.z, f1.w);
      } else xb = make_uint4(0,0,0,0);
    }
    bf16x8 bfrag = asbf(xb);
    #pragma unroll
    for (int nt = 0; nt < 8; ++nt){
      uint4 wa = ((const uint4*)Wt)[(size_t)(nt*16 + li)*16 + (k0>>3)];
      acc[nt] = __builtin_amdgcn_mfma_f32_16x16x32_bf16(asbf(wa), bfrag, acc[nt], 0, 0, 0);
    }
  }
  if (valid){
    float dr = dis[r];
    #pragma unroll
    for (int nt = 0; nt < 8; ++nt){
      uint2 o;
      o.x = pk2(acc[nt][0]*dr, acc[nt][1]*dr);
      o.y = pk2(acc[nt][2]*dr, acc[nt][3]*dr);
      *(uint2*)&Y[(size_t)nt*SLN + (size_t)r*8 + g*2] = o;   // slice-major
    }
  }
}

// ---------------- sliced CSR aggregation + bias + ELU ----------------
// grid = (NN/4, 8 slices), slice in the SLOW dim: all XCDs sweep one 3.2MB
// slice at a time -> gathers hit per-XCD L2. Wave = 1 node; lane = (edge
// subgroup 0..7) x (uint 0..7); 16 edges in flight; shfl_xor butterfly over
// lane bits 3..5 reduces the 8 edge subgroups; eg==0 lanes write 16 channels.
template<int OUT_BF16>
__global__ __launch_bounds__(256) void k_agg(const uint* __restrict__ Hs,
    const int* __restrict__ rowptr, const float* __restrict__ dis,
    const uint* __restrict__ es, const float* __restrict__ bias,
    void* __restrict__ outv){
  int t = threadIdx.x;
  int wv = t >> 6, l = t & 63;
  int u = l & 7, eg = l >> 3;
  int s = blockIdx.y;
  int n = blockIdx.x*4 + wv;              // gridDim.x*4 == NN exactly
  const uint* Hsl = Hs + (size_t)s*SLN;
  int e0 = rowptr[n], e1 = rowptr[n+1];
  float a0 = 0.f, a1 = 0.f, b0 = 0.f, b1 = 0.f;
  int e = e0;
  for (; e + 16 <= e1; e += 16){
    uint sA = es[e + eg];
    uint sB = es[e + 8 + eg];
    uint hA = Hsl[(size_t)sA*8 + u];
    uint hB = Hsl[(size_t)sB*8 + u];
    a0 += __uint_as_float(hA << 16); a1 += __uint_as_float(hA & 0xFFFF0000u);
    b0 += __uint_as_float(hB << 16); b1 += __uint_as_float(hB & 0xFFFF0000u);
  }
  if (e + 8 <= e1){
    uint sA = es[e + eg];
    uint hA = Hsl[(size_t)sA*8 + u];
    a0 += __uint_as_float(hA << 16); a1 += __uint_as_float(hA & 0xFFFF0000u);
    e += 8;
  }
  if (eg < e1 - e){
    uint sA = es[e + eg];
    uint hA = Hsl[(size_t)sA*8 + u];
    b0 += __uint_as_float(hA << 16); b1 += __uint_as_float(hA & 0xFFFF0000u);
  }
  a0 += b0; a1 += b1;
  // butterfly reduce across the 8 edge subgroups (lane bits 3,4,5)
  a0 += __shfl_xor(a0, 8, 64);  a1 += __shfl_xor(a1, 8, 64);
  a0 += __shfl_xor(a0, 16, 64); a1 += __shfl_xor(a1, 16, 64);
  a0 += __shfl_xor(a0, 32, 64); a1 += __shfl_xor(a1, 32, 64);
  float dn = dis[n];
  float2 bb = *(const float2*)&bias[s*16 + u*2];
  float v0 = fmaf(dn, a0, bb.x);
  float v1 = fmaf(dn, a1, bb.y);
  v0 = (v0 > 0.f) ? v0 : expm1f(v0);
  v1 = (v1 > 0.f) ? v1 : expm1f(v1);
  if (eg == 0){
    if (OUT_BF16){
      ((uint*)outv)[(size_t)n*64 + s*8 + u] = pk2(v0, v1);     // packed row-major
    } else {
      float2 o; o.x = v0; o.y = v1;
      *(float2*)&((float*)outv)[(size_t)n*DD + s*16 + u*2] = o;
    }
  }
}

// ---------------- launch ----------------

extern "C" void kernel_launch(void* const* d_in, const int* in_sizes, int n_in,
                              void* d_out, int out_size, void* d_ws, size_t ws_size,
                              hipStream_t stream){
  const float* x  = (const float*)d_in[0];
  const int*   ei = (const int*)d_in[1];   // [2, NE]: src row then dst row
  const float* W1 = (const float*)d_in[2];
  const float* b1 = (const float*)d_in[3];
  const float* W2 = (const float*)d_in[4];
  const float* b2 = (const float*)d_in[5];

  // workspace carve-up (int units), every region 64-int (256B) aligned.
  // R11 BUG FIXED HERE: out1 needs the FULL 6.4M uints (64 packed uints x NN
  // nodes) -- the 3.2M union in R11 spilled agg<1> writes into H while agg<1>
  // was still reading H. out1 now has 6.4M; it still aliases bedge (2.05M,
  // dead after k_build) at its head, which is safe: agg<1> (the only out1
  // writer) runs after k_build. H (written by gemm1) is reused as H2 by gemm2
  // (H dead once agg<1> completes). Total = 14725120 ints = 58.9 MB, the
  // exact footprint R10 proved fits.
  int*   ws_i   = (int*)d_ws;
  int*   gcnt   = ws_i + 0;                 // [0, 8000)  500*16 padded counters
  int*   bbase  = ws_i + 8000;              // [8000, 8576)
  float* dis    = (float*)(ws_i + 8576);    // [8576, 108608)
  int*   rowptr = ws_i + 108608;            // [108608, 208704)  100001 used
  uint*  Wt1    = (uint*)(ws_i + 208704);   // [208704, 216896)  128x128 bf16
  uint*  Wt2    = (uint*)(ws_i + 216896);   // [216896, 225088)
  uint*  es     = (uint*)(ws_i + 225088);   // [225088, 1925120)  1700000 used
  uint*  bedge  = (uint*)(ws_i + 1925120);  // [1925120, 3973120)  2.048M, dead after build
  uint*  out1   = (uint*)(ws_i + 1925120);  // [1925120, 8325120)  6.4M uints, %256==0
  uint*  H      = (uint*)(ws_i + 8325120);  // [8325120, 14725120) 6.4M uints, %256==0
  uint*  H2     = H;                        //   reused: H dead after agg<1>

  k_init  <<<3,   256, 0, stream>>>(W1, W2, Wt1, Wt2, gcnt);
  k_bucket<<<NBK, 256, 0, stream>>>(ei, gcnt, bedge);
  k_bscan <<<1,   512, 0, stream>>>(gcnt, bbase);
  k_build <<<NB,  256, 0, stream>>>(gcnt, bbase, bedge, dis, rowptr, es);

  // layer 1: H = bf16(dis*(x@W1)) slice-major ; out1 = bf16(elu(dis*agg + b1))
  k_gemm<0><<<NBG, 256, 0, stream>>>(x, Wt1, dis, H, NN);
  k_agg<1> <<<dim3(25000, 8), 256, 0, stream>>>(H, rowptr, dis, es, b1, out1);
  // layer 2: H2 = bf16(dis*(out1@W2)) slice-major ; out = elu(dis*agg + b2)
  k_gemm<1><<<NBG, 256, 0, stream>>>(out1, Wt2, dis, H2, NN);
  k_agg<0> <<<dim3(25000, 8), 256, 0, stream>>>(H2, rowptr, dis, es, b2, d_out);
}

// Round 13
// 243.262 us; speedup vs baseline: 2.5184x; 2.5184x over previous
//
#include <hip/hip_runtime.h>
#include <math.h>

#define NN 100000
#define NE 1600000
#define NT (NE + NN)   // 1700000 edges incl. self-loops
#define DD 128
#define NB 500          // dst buckets
#define BR 200          // node range per bucket (NB*BR == NN)
#define BCAP 4096       // bucket capacity (mean 3200, sigma 56 -> 15.9 sigma headroom)
#define NCH 2048        // edges per k_bucket block
#define NBK 782         // ceil(NE/NCH)
#define NBG 1563        // ceil(NN/64) gemm blocks
#define PW 68           // padded LDS row stride in uints (64 + 4 -> 2-way banks only)
#define BMAGIC 21474837u // ceil(2^32/200); exact for d < 100000

typedef unsigned int uint;
typedef unsigned short ushort;
typedef __attribute__((ext_vector_type(8))) short bf16x8;
typedef __attribute__((ext_vector_type(4))) float f32x4;

// round-to-nearest-even fp32 -> bf16 (16-bit payload in a uint)
__device__ __forceinline__ uint bfr(float f){
  uint u = __float_as_uint(f);
  return (u + 0x7FFFu + ((u >> 16) & 1u)) >> 16;
}
__device__ __forceinline__ uint pk2(float a, float b){
  return (bfr(a) & 0xFFFFu) | (bfr(b) << 16);
}
__device__ __forceinline__ bf16x8 asbf(uint4 u){
  union { uint4 u; bf16x8 b; } c; c.u = u; return c.b;
}

// ---------------- init: weight transpose (blocks 0,1) + gcnt zero (block 2) ----------------
__global__ __launch_bounds__(256) void k_init(const float* __restrict__ W1f, const float* __restrict__ W2f,
    uint* __restrict__ Wt1, uint* __restrict__ Wt2, int* __restrict__ gcnt){
  int t = threadIdx.x;
  if (blockIdx.x == 2){
    for (int i = t; i < 8000; i += 256) gcnt[i] = 0;
    return;
  }
  const float* W = blockIdx.x ? W2f : W1f;
  uint* Wt = blockIdx.x ? Wt2 : Wt1;
  int n = t >> 1, k0 = (t & 1) * 64;
  for (int kk = 0; kk < 64; kk += 2){
    float v0 = W[(size_t)(k0+kk  )*DD + n];
    float v1 = W[(size_t)(k0+kk+1)*DD + n];
    Wt[(size_t)n*64 + ((k0+kk)>>1)] = pk2(v0, v1);
  }
}

// ---------------- preprocessing: 2-phase LDS-histogram bucket sort ----------------

__global__ __launch_bounds__(256) void k_bucket(const int* __restrict__ ei,
    int* __restrict__ gcnt, uint* __restrict__ bedge){
  __shared__ uint   ent[NCH];    // src(17b) | d_local(8b)<<17
  __shared__ ushort bbs[NCH];    // bucket id
  __shared__ int    hist[NB];
  __shared__ int    fl[NB];
  __shared__ int    gb[NB];
  int t = threadIdx.x;
  int base = blockIdx.x * NCH;
  int nv = NE - base; if (nv > NCH) nv = NCH;
  for (int b = t; b < NB; b += 256){ hist[b] = 0; fl[b] = 0; }
  __syncthreads();
  for (int j = t; j < nv; j += 256){
    int i = base + j;                      // coalesced
    uint s = (uint)ei[i];
    uint d = (uint)ei[NE + i];
    uint b = __umulhi(d, BMAGIC);          // d / 200
    uint dl = d - b*BR;
    ent[j] = s | (dl << 17);
    bbs[j] = (ushort)b;
    atomicAdd(&hist[b], 1);
  }
  __syncthreads();
  for (int b = t; b < NB; b += 256){
    int h = hist[b];
    gb[b] = h ? atomicAdd(&gcnt[b*16], h) : 0;   // bulk reservation
  }
  __syncthreads();
  for (int j = t; j < nv; j += 256){
    uint b = bbs[j];
    int q = atomicAdd(&fl[b], 1);          // LDS fill
    bedge[(size_t)b*BCAP + gb[b] + q] = ent[j];
  }
}

// single-block exclusive scan of bucket totals (incl. +BR self-loops each)
__global__ __launch_bounds__(512) void k_bscan(const int* __restrict__ gcnt, int* __restrict__ bbase){
  __shared__ int s[512];
  int t = threadIdx.x;
  int v = (t < NB) ? (gcnt[t*16] + BR) : 0;
  s[t] = v;
  __syncthreads();
  for (int off = 1; off < 512; off <<= 1){
    int a = (t >= off) ? s[t-off] : 0;
    __syncthreads();
    s[t] += a;
    __syncthreads();
  }
  if (t < NB) bbase[t] = s[t] - v;
}

// fused per-bucket CSR build: LDS count + scan -> dis/rowptr/es (es = plain src)
__global__ __launch_bounds__(256) void k_build(const int* __restrict__ gcnt,
    const int* __restrict__ bbase, const uint* __restrict__ bedge,
    float* __restrict__ dis, int* __restrict__ rowptr, uint* __restrict__ es){
  __shared__ uint eL[BCAP];
  __shared__ int  cl[BR];
  __shared__ int  fl[BR];
  __shared__ int  pf[256];
  int b = blockIdx.x, t = threadIdx.x;
  int base = bbase[b];
  if (t < BR){ cl[t] = 0; fl[t] = 0; }
  __syncthreads();
  int cnt = gcnt[b*16];
  for (int e = t; e < cnt; e += 256){
    uint u = bedge[(size_t)b*BCAP + e];
    eL[e] = u;
    atomicAdd(&cl[u >> 17], 1);
  }
  __syncthreads();
  // inclusive scan over (cl[i]+1)
  int v = (t < BR) ? (cl[t] + 1) : 0;
  pf[t] = v;
  __syncthreads();
  for (int off = 1; off < 256; off <<= 1){
    int a = (t >= off) ? pf[t-off] : 0;
    __syncthreads();
    pf[t] += a;
    __syncthreads();
  }
  if (t < BR){
    int n  = b*BR + t;
    int p0 = base + pf[t] - v;             // exclusive prefix (globally monotone)
    rowptr[n] = p0;
    dis[n] = rsqrtf((float)(cl[t] + 1));
    es[p0 + cl[t]] = (uint)n;              // self-loop last
  }
  if (b == NB-1 && t == 0) rowptr[NN] = NT;
  __syncthreads();
  for (int e = t; e < cnt; e += 256){
    uint u = eL[e];
    int  dloc = u >> 17;
    int  q  = atomicAdd(&fl[dloc], 1);
    int  p0 = base + pf[dloc] - (cl[dloc] + 1);
    es[p0 + q] = u & 0x1FFFFu;
  }
}

// ---------------- LDS-staged MFMA GEMM -> dis-scaled bf16 row-major ----------------
// Y[r][64 uints] = bf16(dis[r] * (X@W)[r]). 64 rows/block, 256 thr (4 waves).
// Staging (coalesced): Wt -> Ws (128 x PW), X tile -> Xs (64 x PW, packed bf16).
// +4-uint row pad makes all ds_read_b128 fragment reads 2-way-bank only (free).
// Fragment values identical to the R9 zero-LDS version: lane (g,li) holds
// Wt row (nt*16+li) / X row (wv*16+li), k-chunk ks*32+g*8 -> same math.
template<int IN_BF16>
__global__ __launch_bounds__(256, 3) void k_gemm(const void* __restrict__ Xv,
    const uint* __restrict__ Wt, const float* __restrict__ dis,
    uint* __restrict__ Y, int nrows){
  __shared__ uint Ws[128*PW];
  __shared__ uint Xs[64*PW];
  int t = threadIdx.x;
  int row0 = blockIdx.x * 64;

  // stage Wt: 2048 uint4, coalesced
  #pragma unroll
  for (int it = 0; it < 8; ++it){
    int f = it*256 + t;
    uint4 v = ((const uint4*)Wt)[f];
    int row = f >> 4, c4 = f & 15;
    *(uint4*)&Ws[row*PW + c4*4] = v;
  }
  // stage X tile (64 rows), coalesced; zero-fill invalid rows
  if (!IN_BF16){
    const float* X = (const float*)Xv;
    #pragma unroll
    for (int it = 0; it < 8; ++it){
      int f = it*256 + t;                  // 0..2047 float4
      int row = f >> 5, c4 = f & 31;
      int gr = row0 + row;
      float4 v = (gr < nrows) ? ((const float4*)X)[(size_t)gr*32 + c4]
                              : make_float4(0.f,0.f,0.f,0.f);
      uint2 p; p.x = pk2(v.x, v.y); p.y = pk2(v.z, v.w);
      *(uint2*)&Xs[row*PW + c4*2] = p;
    }
  } else {
    const uint* X = (const uint*)Xv;
    #pragma unroll
    for (int it = 0; it < 4; ++it){
      int f = it*256 + t;                  // 0..1023 uint4
      int row = f >> 4, c4 = f & 15;
      int gr = row0 + row;
      uint4 v = (gr < nrows) ? ((const uint4*)X)[(size_t)gr*16 + c4]
                             : make_uint4(0,0,0,0);
      *(uint4*)&Xs[row*PW + c4*4] = v;
    }
  }
  __syncthreads();

  int wv = t >> 6, l = t & 63;
  int g = l >> 4, li = l & 15;
  int rb = wv*16 + li;                    // row within block
  int r  = row0 + rb;
  f32x4 acc[8];
  #pragma unroll
  for (int i = 0; i < 8; ++i) acc[i] = (f32x4){0.f,0.f,0.f,0.f};

  #pragma unroll
  for (int ks = 0; ks < 4; ++ks){
    int c = (ks*4 + g)*4;                 // uint offset of this lane's k-chunk
    bf16x8 bfrag = asbf(*(const uint4*)&Xs[rb*PW + c]);
    #pragma unroll
    for (int nt = 0; nt < 8; ++nt){
      bf16x8 afrag = asbf(*(const uint4*)&Ws[(nt*16 + li)*PW + c]);
      acc[nt] = __builtin_amdgcn_mfma_f32_16x16x32_bf16(afrag, bfrag, acc[nt], 0, 0, 0);
    }
  }
  if (r < nrows){
    float dr = dis[r];
    #pragma unroll
    for (int nt = 0; nt < 8; ++nt){
      uint2 o;
      o.x = pk2(acc[nt][0]*dr, acc[nt][1]*dr);
      o.y = pk2(acc[nt][2]*dr, acc[nt][3]*dr);
      *(uint2*)&Y[(size_t)r*64 + nt*8 + g*2] = o;   // row-major packed
    }
  }
}

// ---------------- CSR aggregation + bias + ELU (flat, R9-proven) ----------------
// out[n] = elu(dis[n] * sum_{s in N(n)} H'[s] + b); H' rows pre-scaled by dis[s].
// one WAVE per node (4 nodes / 256-thread block); lane = bf16 channel pair;
// 16x edge unroll -> 16 gathers in flight per wave.
template<int OUT_BF16>
__global__ __launch_bounds__(256) void k_agg(const uint* __restrict__ H,
    const int* __restrict__ rowptr, const float* __restrict__ dis,
    const uint* __restrict__ es, const float* __restrict__ bias,
    void* __restrict__ outv){
  int wid  = threadIdx.x >> 6;
  int lane = threadIdx.x & 63;
  int n = blockIdx.x*4 + wid;            // grid*4 == NN exactly
  int e0 = rowptr[n];
  int e1 = rowptr[n+1];
  float a0 = 0.f, a1 = 0.f, a2 = 0.f, a3 = 0.f;
  int e = e0;

#define ASTEP(k,A,B) { uint s##k = es[e+k]; \
    uint h##k = H[(size_t)s##k*64 + lane]; \
    A += __uint_as_float(h##k << 16); \
    B += __uint_as_float(h##k & 0xFFFF0000u); }

  for (; e + 16 <= e1; e += 16){
    ASTEP( 0,a0,a1) ASTEP( 1,a2,a3) ASTEP( 2,a0,a1) ASTEP( 3,a2,a3)
    ASTEP( 4,a0,a1) ASTEP( 5,a2,a3) ASTEP( 6,a0,a1) ASTEP( 7,a2,a3)
    ASTEP( 8,a0,a1) ASTEP( 9,a2,a3) ASTEP(10,a0,a1) ASTEP(11,a2,a3)
    ASTEP(12,a0,a1) ASTEP(13,a2,a3) ASTEP(14,a0,a1) ASTEP(15,a2,a3)
  }
  for (; e + 4 <= e1; e += 4){
    ASTEP(0,a0,a1) ASTEP(1,a2,a3) ASTEP(2,a0,a1) ASTEP(3,a2,a3)
  }
  for (; e < e1; ++e){
    ASTEP(0,a0,a1)
  }
#undef ASTEP

  float dn = dis[n];
  float2 b = *(const float2*)&bias[lane*2];
  float v0 = fmaf(dn, a0 + a2, b.x);
  float v1 = fmaf(dn, a1 + a3, b.y);
  v0 = (v0 > 0.f) ? v0 : expm1f(v0);
  v1 = (v1 > 0.f) ? v1 : expm1f(v1);
  if (OUT_BF16){
    ((uint*)outv)[(size_t)n*64 + lane] = pk2(v0, v1);
  } else {
    float2 o; o.x = v0; o.y = v1;
    *(float2*)&((float*)outv)[(size_t)n*DD + lane*2] = o;
  }
}

// ---------------- launch ----------------

extern "C" void kernel_launch(void* const* d_in, const int* in_sizes, int n_in,
                              void* d_out, int out_size, void* d_ws, size_t ws_size,
                              hipStream_t stream){
  const float* x  = (const float*)d_in[0];
  const int*   ei = (const int*)d_in[1];   // [2, NE]: src row then dst row
  const float* W1 = (const float*)d_in[2];
  const float* b1 = (const float*)d_in[3];
  const float* W2 = (const float*)d_in[4];
  const float* b2 = (const float*)d_in[5];

  // workspace carve-up (int units), every region 64-int (256B) aligned.
  // H alignment is CRITICAL (misaligned 256B rows -> +42% gather FETCH, R4..R8).
  // out1 = FULL 6.4M uints (R11 bug: a 3.2M union clobbered H mid-agg).
  // out1 aliases bedge (2.05M, dead after k_build) at its head -- safe, the
  // only out1 writer (agg<1>) runs after k_build. H2 = H (H dead after agg<1>).
  int*   ws_i   = (int*)d_ws;
  int*   gcnt   = ws_i + 0;                 // [0, 8000)  500*16 padded counters
  int*   bbase  = ws_i + 8000;              // [8000, 8576)
  float* dis    = (float*)(ws_i + 8576);    // [8576, 108608)
  int*   rowptr = ws_i + 108608;            // [108608, 208704)  100001 used
  uint*  Wt1    = (uint*)(ws_i + 208704);   // [208704, 216896)  128x128 bf16
  uint*  Wt2    = (uint*)(ws_i + 216896);   // [216896, 225088)
  uint*  es     = (uint*)(ws_i + 225088);   // [225088, 1925120)  1700000 used
  uint*  bedge  = (uint*)(ws_i + 1925120);  // [1925120, 3973120)  dead after build
  uint*  out1   = (uint*)(ws_i + 1925120);  // [1925120, 8325120)  6.4M uints, %256==0
  uint*  H      = (uint*)(ws_i + 8325120);  // [8325120, 14725120) 6.4M uints, %256==0
  uint*  H2     = H;                        //   reused: H dead after agg<1>
  // total 14725120 ints = 58.9 MB (proven fits, R10/R12)

  k_init  <<<3,   256, 0, stream>>>(W1, W2, Wt1, Wt2, gcnt);
  k_bucket<<<NBK, 256, 0, stream>>>(ei, gcnt, bedge);
  k_bscan <<<1,   512, 0, stream>>>(gcnt, bbase);
  k_build <<<NB,  256, 0, stream>>>(gcnt, bbase, bedge, dis, rowptr, es);

  // layer 1: H = bf16(dis*(x@W1)) ; out1 = bf16(elu(dis*agg + b1))
  k_gemm<0><<<NBG, 256, 0, stream>>>(x, Wt1, dis, H, NN);
  k_agg<1> <<<25000, 256, 0, stream>>>(H, rowptr, dis, es, b1, out1);
  // layer 2: H2 = bf16(dis*(out1@W2)) ; out = elu(dis*agg + b2)
  k_gemm<1><<<NBG, 256, 0, stream>>>(out1, Wt2, dis, H2, NN);
  k_agg<0> <<<25000, 256, 0, stream>>>(H2, rowptr, dis, es, b2, d_out);
}

// Round 14
// 233.724 us; speedup vs baseline: 2.6211x; 1.0408x over previous
//
#include <hip/hip_runtime.h>
#include <math.h>

#define NN 100000
#define NE 1600000
#define NT (NE + NN)   // 1700000 edges incl. self-loops
#define DD 128
#define NB 500          // dst buckets
#define BR 200          // node range per bucket (NB*BR == NN)
#define BCAP 4096       // bucket capacity (mean 3200, sigma 56 -> 15.9 sigma headroom)
#define NCH 2048        // edges per k_bucket block
#define NBK 782         // ceil(NE/NCH)
#define NBG 1563        // ceil(NN/64) gemm blocks
#define PW 68           // padded LDS row stride in uints (64 + 4 -> 2-way banks only)
#define BMAGIC 21474837u // ceil(2^32/200); exact for d < 100000

typedef unsigned int uint;
typedef unsigned short ushort;
typedef __attribute__((ext_vector_type(8))) short bf16x8;
typedef __attribute__((ext_vector_type(4))) float f32x4;

// round-to-nearest-even fp32 -> bf16 (16-bit payload in a uint)
__device__ __forceinline__ uint bfr(float f){
  uint u = __float_as_uint(f);
  return (u + 0x7FFFu + ((u >> 16) & 1u)) >> 16;
}
__device__ __forceinline__ uint pk2(float a, float b){
  return (bfr(a) & 0xFFFFu) | (bfr(b) << 16);
}
__device__ __forceinline__ bf16x8 asbf(uint4 u){
  union { uint4 u; bf16x8 b; } c; c.u = u; return c.b;
}

// ---------------- K2: fused [Wt transpose (blocks 0,1) | bucket sort (782)] ----------------
__global__ __launch_bounds__(256) void k_pre1(const float* __restrict__ W1f, const float* __restrict__ W2f,
    uint* __restrict__ Wt1, uint* __restrict__ Wt2,
    const int* __restrict__ ei, int* __restrict__ gcnt, uint* __restrict__ bedge){
  __shared__ uint   ent[NCH];    // src(17b) | d_local(8b)<<17
  __shared__ ushort bbs[NCH];    // bucket id
  __shared__ int    hist[NB];
  __shared__ int    fl[NB];
  __shared__ int    gb[NB];
  int t = threadIdx.x;
  if (blockIdx.x < 2){
    const float* W = blockIdx.x ? W2f : W1f;
    uint* Wt = blockIdx.x ? Wt2 : Wt1;
    int n = t >> 1, k0 = (t & 1) * 64;
    for (int kk = 0; kk < 64; kk += 2){
      float v0 = W[(size_t)(k0+kk  )*DD + n];
      float v1 = W[(size_t)(k0+kk+1)*DD + n];
      Wt[(size_t)n*64 + ((k0+kk)>>1)] = pk2(v0, v1);
    }
    return;
  }
  int bid = blockIdx.x - 2;
  int base = bid * NCH;
  int nv = NE - base; if (nv > NCH) nv = NCH;
  for (int b = t; b < NB; b += 256){ hist[b] = 0; fl[b] = 0; }
  __syncthreads();
  for (int j = t; j < nv; j += 256){
    int i = base + j;                      // coalesced
    uint s = (uint)ei[i];
    uint d = (uint)ei[NE + i];
    uint b = __umulhi(d, BMAGIC);          // d / 200
    uint dl = d - b*BR;
    ent[j] = s | (dl << 17);
    bbs[j] = (ushort)b;
    atomicAdd(&hist[b], 1);
  }
  __syncthreads();
  for (int b = t; b < NB; b += 256){
    int h = hist[b];
    gb[b] = h ? atomicAdd(&gcnt[b*16], h) : 0;   // bulk reservation
  }
  __syncthreads();
  for (int j = t; j < nv; j += 256){
    uint b = bbs[j];
    int q = atomicAdd(&fl[b], 1);          // LDS fill
    bedge[(size_t)b*BCAP + gb[b] + q] = ent[j];
  }
}

// ---------------- K3: fused [bucket-total exclusive scan (block 0) | per-bucket degree->deg,dis (500)] ----------------
__global__ __launch_bounds__(256) void k_pre2(const int* __restrict__ gcnt, int* __restrict__ bbase,
    const uint* __restrict__ bedge, int* __restrict__ deg, float* __restrict__ dis){
  __shared__ int sm[256];
  int t = threadIdx.x;
  if (blockIdx.x == 0){
    // 2 buckets per thread: scan pair-sums, emit both exclusive offsets
    int i0 = 2*t, i1 = 2*t + 1;
    int v0 = (i0 < NB) ? (gcnt[i0*16] + BR) : 0;
    int v1 = (i1 < NB) ? (gcnt[i1*16] + BR) : 0;
    int p = v0 + v1;
    sm[t] = p;
    __syncthreads();
    for (int off = 1; off < 256; off <<= 1){
      int a = (t >= off) ? sm[t-off] : 0;
      __syncthreads();
      sm[t] += a;
      __syncthreads();
    }
    int excl = sm[t] - p;
    if (i0 < NB) bbase[i0] = excl;
    if (i1 < NB) bbase[i1] = excl + v0;
    return;
  }
  int b = blockIdx.x - 1;
  int* cl = sm;                            // BR <= 256
  if (t < BR) cl[t] = 0;
  __syncthreads();
  int cnt = gcnt[b*16];
  for (int e = t; e < cnt; e += 256){
    atomicAdd(&cl[bedge[(size_t)b*BCAP + e] >> 17], 1);
  }
  __syncthreads();
  if (t < BR){
    int n = b*BR + t;
    int dg = cl[t];
    deg[n] = dg;                           // in-degree excl self-loop
    dis[n] = rsqrtf((float)(dg + 1));
  }
}

// ---------------- shared GEMM body: Y[r] = bf16(dis[r] * (X@W)[r]) ----------------
// 64 rows/block. Staging coalesced into padded LDS (2-way banks only);
// fragments via ds_read_b128; lane (g,li): Wt row nt*16+li, X row wv*16+li,
// k-chunk ks*32+g*8. C/D: lane owns row r, cols nt*16+g*4+reg (HW-verified).
template<int IN_BF16>
__device__ __forceinline__ void gemm_body(uint* __restrict__ Ws, uint* __restrict__ Xs,
    const void* __restrict__ Xv, const uint* __restrict__ Wt,
    const float* __restrict__ dis, uint* __restrict__ Y, int row0){
  int t = threadIdx.x;
  // stage Wt: 2048 uint4, coalesced
  #pragma unroll
  for (int it = 0; it < 8; ++it){
    int f = it*256 + t;
    uint4 v = ((const uint4*)Wt)[f];
    int row = f >> 4, c4 = f & 15;
    *(uint4*)&Ws[row*PW + c4*4] = v;
  }
  // stage X tile (64 rows), coalesced; zero-fill invalid rows
  if (!IN_BF16){
    const float* X = (const float*)Xv;
    #pragma unroll
    for (int it = 0; it < 8; ++it){
      int f = it*256 + t;                  // 0..2047 float4
      int row = f >> 5, c4 = f & 31;
      int gr = row0 + row;
      float4 v = (gr < NN) ? ((const float4*)X)[(size_t)gr*32 + c4]
                           : make_float4(0.f,0.f,0.f,0.f);
      uint2 p; p.x = pk2(v.x, v.y); p.y = pk2(v.z, v.w);
      *(uint2*)&Xs[row*PW + c4*2] = p;
    }
  } else {
    const uint* X = (const uint*)Xv;
    #pragma unroll
    for (int it = 0; it < 4; ++it){
      int f = it*256 + t;                  // 0..1023 uint4
      int row = f >> 4, c4 = f & 15;
      int gr = row0 + row;
      uint4 v = (gr < NN) ? ((const uint4*)X)[(size_t)gr*16 + c4]
                          : make_uint4(0,0,0,0);
      *(uint4*)&Xs[row*PW + c4*4] = v;
    }
  }
  __syncthreads();

  int wv = t >> 6, l = t & 63;
  int g = l >> 4, li = l & 15;
  int rb = wv*16 + li;                    // row within block
  int r  = row0 + rb;
  f32x4 acc[8];
  #pragma unroll
  for (int i = 0; i < 8; ++i) acc[i] = (f32x4){0.f,0.f,0.f,0.f};

  #pragma unroll
  for (int ks = 0; ks < 4; ++ks){
    int c = (ks*4 + g)*4;                 // uint offset of this lane's k-chunk
    bf16x8 bfrag = asbf(*(const uint4*)&Xs[rb*PW + c]);
    #pragma unroll
    for (int nt = 0; nt < 8; ++nt){
      bf16x8 afrag = asbf(*(const uint4*)&Ws[(nt*16 + li)*PW + c]);
      acc[nt] = __builtin_amdgcn_mfma_f32_16x16x32_bf16(afrag, bfrag, acc[nt], 0, 0, 0);
    }
  }
  if (r < NN){
    float dr = dis[r];
    #pragma unroll
    for (int nt = 0; nt < 8; ++nt){
      uint2 o;
      o.x = pk2(acc[nt][0]*dr, acc[nt][1]*dr);
      o.y = pk2(acc[nt][2]*dr, acc[nt][3]*dr);
      *(uint2*)&Y[(size_t)r*64 + nt*8 + g*2] = o;   // row-major packed
    }
  }
}

// ---------------- K4: fused [CSR build (blocks 0..499) | layer-1 GEMM (500..2062)] ----------------
// Build and gemm1 are independent after k_pre2 -> co-resident heterogeneous work.
// Build's LDS aliases the gemm's 52.2KB buffer (disjoint branches) -> 3 blocks/CU.
__global__ __launch_bounds__(256, 3) void k_bg(const int* __restrict__ gcnt,
    const int* __restrict__ bbase, const uint* __restrict__ bedge,
    const int* __restrict__ deg, const float* __restrict__ dis,
    int* __restrict__ rowptr, uint* __restrict__ es,
    const float* __restrict__ X, const uint* __restrict__ Wt1, uint* __restrict__ H){
  __shared__ uint smem[192*PW];           // gemm: Ws|Xs ; build: cl|fl|pf
  int t = threadIdx.x;
  if (blockIdx.x >= NB){
    gemm_body<0>(smem, smem + 128*PW, X, Wt1, dis, H, (blockIdx.x - NB)*64);
    return;
  }
  int b = blockIdx.x;
  int base = bbase[b];
  int* cl = (int*)smem;
  int* fl = cl + BR;
  int* pf = cl + 2*BR;                    // 256 ints
  if (t < BR){ cl[t] = deg[b*BR + t]; fl[t] = 0; }
  __syncthreads();
  // inclusive scan over (cl[i]+1)
  int v = (t < BR) ? (cl[t] + 1) : 0;
  pf[t] = v;
  __syncthreads();
  for (int off = 1; off < 256; off <<= 1){
    int a = (t >= off) ? pf[t-off] : 0;
    __syncthreads();
    pf[t] += a;
    __syncthreads();
  }
  if (t < BR){
    int n  = b*BR + t;
    int p0 = base + pf[t] - v;             // exclusive prefix (globally monotone)
    rowptr[n] = p0;
    es[p0 + cl[t]] = (uint)n;              // self-loop last
  }
  if (b == NB-1 && t == 0) rowptr[NN] = NT;
  __syncthreads();
  int cnt = gcnt[b*16];
  for (int e = t; e < cnt; e += 256){
    uint u = bedge[(size_t)b*BCAP + e];
    int  dloc = u >> 17;
    int  q  = atomicAdd(&fl[dloc], 1);
    int  p0 = base + pf[dloc] - (cl[dloc] + 1);
    es[p0 + q] = u & 0x1FFFFu;
  }
}

// ---------------- layer-2 GEMM (bf16 input) ----------------
__global__ __launch_bounds__(256, 3) void k_gemm2(const uint* __restrict__ X,
    const uint* __restrict__ Wt, const float* __restrict__ dis, uint* __restrict__ Y){
  __shared__ uint smem[192*PW];
  gemm_body<1>(smem, smem + 128*PW, X, Wt, dis, Y, blockIdx.x*64);
}

// ---------------- CSR aggregation + bias + ELU (flat, R9-proven) ----------------
// out[n] = elu(dis[n] * sum_{s in N(n)} H'[s] + b); H' rows pre-scaled by dis[s].
// one WAVE per node (4 nodes / 256-thread block); lane = bf16 channel pair;
// 16x edge unroll -> 16 gathers in flight per wave.
template<int OUT_BF16>
__global__ __launch_bounds__(256) void k_agg(const uint* __restrict__ H,
    const int* __restrict__ rowptr, const float* __restrict__ dis,
    const uint* __restrict__ es, const float* __restrict__ bias,
    void* __restrict__ outv){
  int wid  = threadIdx.x >> 6;
  int lane = threadIdx.x & 63;
  int n = blockIdx.x*4 + wid;            // grid*4 == NN exactly
  int e0 = rowptr[n];
  int e1 = rowptr[n+1];
  float a0 = 0.f, a1 = 0.f, a2 = 0.f, a3 = 0.f;
  int e = e0;

#define ASTEP(k,A,B) { uint s##k = es[e+k]; \
    uint h##k = H[(size_t)s##k*64 + lane]; \
    A += __uint_as_float(h##k << 16); \
    B += __uint_as_float(h##k & 0xFFFF0000u); }

  for (; e + 16 <= e1; e += 16){
    ASTEP( 0,a0,a1) ASTEP( 1,a2,a3) ASTEP( 2,a0,a1) ASTEP( 3,a2,a3)
    ASTEP( 4,a0,a1) ASTEP( 5,a2,a3) ASTEP( 6,a0,a1) ASTEP( 7,a2,a3)
    ASTEP( 8,a0,a1) ASTEP( 9,a2,a3) ASTEP(10,a0,a1) ASTEP(11,a2,a3)
    ASTEP(12,a0,a1) ASTEP(13,a2,a3) ASTEP(14,a0,a1) ASTEP(15,a2,a3)
  }
  for (; e + 4 <= e1; e += 4){
    ASTEP(0,a0,a1) ASTEP(1,a2,a3) ASTEP(2,a0,a1) ASTEP(3,a2,a3)
  }
  for (; e < e1; ++e){
    ASTEP(0,a0,a1)
  }
#undef ASTEP

  float dn = dis[n];
  float2 b = *(const float2*)&bias[lane*2];
  float v0 = fmaf(dn, a0 + a2, b.x);
  float v1 = fmaf(dn, a1 + a3, b.y);
  v0 = (v0 > 0.f) ? v0 : expm1f(v0);
  v1 = (v1 > 0.f) ? v1 : expm1f(v1);
  if (OUT_BF16){
    ((uint*)outv)[(size_t)n*64 + lane] = pk2(v0, v1);
  } else {
    float2 o; o.x = v0; o.y = v1;
    *(float2*)&((float*)outv)[(size_t)n*DD + lane*2] = o;
  }
}

// ---------------- launch ----------------

extern "C" void kernel_launch(void* const* d_in, const int* in_sizes, int n_in,
                              void* d_out, int out_size, void* d_ws, size_t ws_size,
                              hipStream_t stream){
  const float* x  = (const float*)d_in[0];
  const int*   ei = (const int*)d_in[1];   // [2, NE]: src row then dst row
  const float* W1 = (const float*)d_in[2];
  const float* b1 = (const float*)d_in[3];
  const float* W2 = (const float*)d_in[4];
  const float* b2 = (const float*)d_in[5];

  // workspace carve-up (int units), every region 64-int (256B) aligned.
  // H alignment is CRITICAL (misaligned 256B rows -> +42% gather FETCH, R4..R8).
  // out1 = FULL 6.4M uints (R11 lesson); aliases bedge (dead after k_bg's
  // build blocks) -- safe: agg<1> (only out1 writer) runs after k_bg.
  // H2 = H (H dead after agg<1>).
  int*   ws_i   = (int*)d_ws;
  int*   gcnt   = ws_i + 0;                 // [0, 8000)  500*16 padded counters
  int*   bbase  = ws_i + 8000;              // [8000, 8576)
  float* dis    = (float*)(ws_i + 8576);    // [8576, 108608)
  int*   rowptr = ws_i + 108608;            // [108608, 208704)  100001 used
  int*   deg    = ws_i + 208704;            // [208704, 308736)  100000 used
  uint*  Wt1    = (uint*)(ws_i + 308736);   // [308736, 316928)  128x128 bf16
  uint*  Wt2    = (uint*)(ws_i + 316928);   // [316928, 325120)
  uint*  es     = (uint*)(ws_i + 325120);   // [325120, 2025152)  1700000 used
  uint*  bedge  = (uint*)(ws_i + 2025152);  // [2025152, 4073152)  dead after k_bg
  uint*  out1   = (uint*)(ws_i + 2025152);  // [2025152, 8425152)  6.4M uints, %256==0
  uint*  H      = (uint*)(ws_i + 8425152);  // [8425152, 14825152) 6.4M uints, %256==0
  uint*  H2     = H;                        //   reused: H dead after agg<1>
  // total 14825152 ints = 59.3 MB (<= 66.4 MB proven in R1)

  hipMemsetAsync(gcnt, 0, 8000*sizeof(int), stream);

  // K2: [Wt transpose | bucket sort]
  k_pre1<<<NBK + 2, 256, 0, stream>>>(W1, W2, Wt1, Wt2, ei, gcnt, bedge);
  // K3: [bucket-total scan | degree histogram -> deg, dis]
  k_pre2<<<NB + 1,  256, 0, stream>>>(gcnt, bbase, bedge, deg, dis);
  // K4: [CSR build | layer-1 GEMM: H = bf16(dis*(x@W1))]  (independent halves)
  k_bg  <<<NB + NBG,256, 0, stream>>>(gcnt, bbase, bedge, deg, dis, rowptr, es, x, Wt1, H);
  // layer-1 agg: out1 = bf16(elu(dis*agg(H) + b1))
  k_agg<1><<<25000, 256, 0, stream>>>(H, rowptr, dis, es, b1, out1);
  // layer-2 GEMM: H2 = bf16(dis*(out1@W2))
  k_gemm2 <<<NBG,   256, 0, stream>>>(out1, Wt2, dis, H2);
  // layer-2 agg: out = elu(dis*agg(H2) + b2)
  k_agg<0><<<25000, 256, 0, stream>>>(H2, rowptr, dis, es, b2, d_out);
}